// Round 7
// baseline (691.414 us; speedup 1.0000x reference)
//
#include <hip/hip_runtime.h>

// Problem constants (B=8, L=1024, D=1024, H=16, DH=64)
#define B_  8
#define L_  1024
#define D_  1024
#define H_  16
#define DH_ 64

typedef unsigned short u16;
typedef __attribute__((ext_vector_type(8))) short short8;      // 8 x u16 bag (bf16)
typedef __attribute__((ext_vector_type(8))) _Float16 half8;    // 8 x f16
typedef __attribute__((ext_vector_type(4))) float floatx4;     // 16x16 C/D frag
typedef __attribute__((ext_vector_type(16))) float floatx16;   // 32x32 C/D frag

// fp32 -> bf16 round-to-nearest-even
static __device__ __forceinline__ u16 f2bf(float f) {
  union { float f; unsigned u; } cv; cv.f = f;
  unsigned u = cv.u;
  return (u16)((u + 0x7fffu + ((u >> 16) & 1u)) >> 16);
}
// fp32 -> f16 (RNE)
static __device__ __forceinline__ u16 f2h(float f) {
  union { _Float16 h; u16 u; } cv; cv.h = (_Float16)f; return cv.u;
}
// pack two fp32 -> two bf16 (round-half-up; nonneg softmax weights) via v_perm
static __device__ __forceinline__ unsigned pack_bf2(float a, float b) {
  union { float f; unsigned u; } ua, ub; ua.f = a; ub.f = b;
  return __builtin_amdgcn_perm(ub.u + 0x8000u, ua.u + 0x8000u, 0x07060302u);
}

#if __has_builtin(__builtin_amdgcn_exp2f)
#define EXP2(x) __builtin_amdgcn_exp2f(x)
#else
#define EXP2(x) __expf((x) * 0.6931471805599453f)
#endif

// ---------------------------------------------------------------- fused casts + bias permute
__global__ void cast_all(const float* __restrict__ x,  const float* __restrict__ wq,
                         const float* __restrict__ wk, const float* __restrict__ wv,
                         const float* __restrict__ wo, const float* __restrict__ mask,
                         u16* __restrict__ xf,  u16* __restrict__ wqf,
                         u16* __restrict__ wkf, u16* __restrict__ wvf,
                         u16* __restrict__ wof, float* __restrict__ biasP) {
  int blk = blockIdx.x;
  if (blk >= 12288) {
    int i = (blk - 12288) * 256 + threadIdx.x;
    int e = i & 3, lane = (i >> 2) & 63, rr = (i >> 8) & 3, t = (i >> 10) & 1;
    int c = (i >> 11) & 15, w = (i >> 15) & 3, qt = i >> 17;
    int kk  = e + 8 * rr + 4 * (lane >> 5);
    int row = qt * 128 + w * 32 + (lane & 31);
    int key = c * 64 + t * 32 + kk;
    // log2e * ((mask-1)*1.25e8 - 24)
    biasP[i] = (mask[(size_t)row * L_ + key] - 1.0f) * 1.8033688e8f - 34.624681f;
    return;
  }
  const float* src; u16* dst; int off;
  if (blk < 8192)       { src = x;  dst = xf;  off = blk; }
  else if (blk < 9216)  { src = wq; dst = wqf; off = blk - 8192; }
  else if (blk < 10240) { src = wk; dst = wkf; off = blk - 9216; }
  else if (blk < 11264) { src = wv; dst = wvf; off = blk - 10240; }
  else                  { src = wo; dst = wof; off = blk - 11264; }
  int i = off * 1024 + threadIdx.x * 4;
  float4 f = *(const float4*)(src + i);
  ushort4 r;
  r.x = f2h(f.x); r.y = f2h(f.y); r.z = f2h(f.z); r.w = f2h(f.w);
  *(ushort4*)(dst + i) = r;
}

// ---------------------------------------------------------------- LDS staging helper
typedef __attribute__((address_space(3))) void  lds_void;
typedef const __attribute__((address_space(1))) void g_void;
static __device__ __forceinline__ void load_lds16(const void* g, void* l) {
  __builtin_amdgcn_global_load_lds((g_void*)g, (lds_void*)l, 16, 0, 0);
}

// ---------------------------------------------------------------- fused QKV GEMM, 256x256, 2-resident
// grid (12, 32), 512 threads (8 waves 2Mx4N, per-wave 128x64 -> LDS:MFMA 1.5:1).
// BK=32, 32 K-tiles, DOUBLE-buffered LDS (64 KB total -> 2 blocks/CU; second
// block's waves cover stage/drain bubbles via TLP). 2 phases/tile, setprio
// around MFMA clusters; all 4 stage loads for tile t+1 issued in phase 0 of
// tile t (~2 phases of latency cover before the publish wait).
//
// LDS layout per buffer, paired-row + chunk-XOR swizzle (PMC: 0 conflicts):
//   u16 buf[128*64]; chunk c' at rho holds logical c = c'^(rho&7);
//   m-row = rho + 128*(c>=4); kb = c&3 (k-chunk of 8 f16)
__global__ __launch_bounds__(512, 4) void gemm_qkv(const u16* __restrict__ A,
                                                   const u16* __restrict__ wq,
                                                   const u16* __restrict__ wk,
                                                   const u16* __restrict__ wv,
                                                   u16* __restrict__ qf,
                                                   u16* __restrict__ kf,
                                                   u16* __restrict__ vb) {
  const int K = D_;
  __shared__ u16 lA2[2 * 8192];    // 32 KB: 2 bufs x 256x32 f16
  __shared__ u16 lB2[2 * 8192];    // 32 KB

  // bijective XCD swizzle over 384 blocks (384 = 8 * 48)
  int flat = blockIdx.y * 12 + blockIdx.x;
  int swz  = (flat & 7) * 48 + (flat >> 3);
  int nb   = swz % 12;
  int mb   = swz / 12;

  const u16* Bw; u16* Cp; float scale; int obf;
  int wsel = nb >> 2;
  if (wsel == 0)      { Bw = wq; Cp = qf; scale = 0.18033688f; obf = 0; }  // 0.125*log2e
  else if (wsel == 1) { Bw = wk; Cp = kf; scale = 1.0f;        obf = 0; }
  else                { Bw = wv; Cp = vb; scale = 1.0f;        obf = 1; }
  const int m0g = mb * 256;
  const int n0w = (nb & 3) * 256;  // row offset within the 1024-row weight

  const int tid  = threadIdx.x;
  const int wid  = tid >> 6;
  const int lane = tid & 63;
  const int m16  = lane & 15;
  const int kg   = lane >> 4;
  const int xorv = m16 & 7;
  const int wm   = wid >> 2;       // 0-1 (128-row half)
  const int wn   = wid & 3;        // 0-3 (64-col strip)

  // fragment-read base offsets (u16 units)
  const int ldaBase = m16 * 64 + (((wm * 4 + kg) ^ xorv) * 8);
  const int ldbBase = ((wn & 1) * 64 + m16) * 64 + ((((wn >> 1) * 4 + kg) ^ xorv) * 8);

  // staging decode: load j covers chunk c_lds = j*512 + tid
  const int cl0 = tid,       rho0 = cl0 >> 3;
  const int c0  = (cl0 & 7) ^ (rho0 & 7);
  const int mr0 = rho0 + ((c0 >> 2) << 7), kb0 = c0 & 3;
  const int cl1 = 512 + tid, rho1 = cl1 >> 3;
  const int c1  = (cl1 & 7) ^ (rho1 & 7);
  const int mr1 = rho1 + ((c1 >> 2) << 7), kb1 = c1 & 3;

  const u16* srcA0 = A  + (size_t)(m0g + mr0) * K + kb0 * 8;
  const u16* srcA1 = A  + (size_t)(m0g + mr1) * K + kb1 * 8;
  const u16* srcB0 = Bw + (size_t)(n0w + mr0) * K + kb0 * 8;
  const u16* srcB1 = Bw + (size_t)(n0w + mr1) * K + kb1 * 8;
  const int dst0 = wid * 512;          // j=0 chunk block
  const int dst1 = 4096 + wid * 512;   // j=1

  floatx4 acc[8][4];
#pragma unroll
  for (int i = 0; i < 8; ++i)
#pragma unroll
    for (int j = 0; j < 4; ++j)
#pragma unroll
      for (int r = 0; r < 4; ++r) acc[i][j][r] = 0.0f;

  // prologue: stage tile 0 into buf 0; publish
  load_lds16(srcA0, lA2 + dst0);
  load_lds16(srcB0, lB2 + dst0);
  load_lds16(srcA1, lA2 + dst1);
  load_lds16(srcB1, lB2 + dst1);
  asm volatile("s_waitcnt vmcnt(0)" ::: "memory");
  __builtin_amdgcn_s_barrier();

  auto TILE = [&](int t, int buf) {
    const u16* bA = lA2 + buf * 8192;
    const u16* bB = lB2 + buf * 8192;
    const int nx = (t + 1) * 32;
    const int ob = (buf ^ 1) * 8192;
    half8 af[8], bf[4];
    // ---- phase 0: frags (A 0-3, B 0-3) + ALL 4 stage loads of tile t+1
#pragma unroll
    for (int i = 0; i < 4; ++i) af[i] = *(const half8*)&bA[ldaBase + i * 1024];
#pragma unroll
    for (int i = 0; i < 4; ++i) bf[i] = *(const half8*)&bB[ldbBase + i * 1024];
    if (t + 1 < 32) {
      load_lds16(srcA0 + nx, lA2 + ob + dst0);
      load_lds16(srcB0 + nx, lB2 + ob + dst0);
      load_lds16(srcA1 + nx, lA2 + ob + dst1);
      load_lds16(srcB1 + nx, lB2 + ob + dst1);
    }
    __builtin_amdgcn_s_barrier();
    __builtin_amdgcn_s_setprio(1);
#pragma unroll
    for (int i = 0; i < 4; ++i)
#pragma unroll
      for (int j = 0; j < 4; ++j)
        acc[i][j] = __builtin_amdgcn_mfma_f32_16x16x32_f16(af[i], bf[j], acc[i][j], 0, 0, 0);
    __builtin_amdgcn_s_setprio(0);
    __builtin_amdgcn_s_barrier();
    // ---- phase 1: frags (A 4-7), pure LDS+MFMA
#pragma unroll
    for (int i = 4; i < 8; ++i) af[i] = *(const half8*)&bA[ldaBase + i * 1024];
    __builtin_amdgcn_s_barrier();
    __builtin_amdgcn_s_setprio(1);
#pragma unroll
    for (int i = 4; i < 8; ++i)
#pragma unroll
      for (int j = 0; j < 4; ++j)
        acc[i][j] = __builtin_amdgcn_mfma_f32_16x16x32_f16(af[i], bf[j], acc[i][j], 0, 0, 0);
    __builtin_amdgcn_s_setprio(0);
    // publish tile t+1 (loads were issued ~2 phases ago)
    if (t + 1 < 32) asm volatile("s_waitcnt vmcnt(0)" ::: "memory");
    __builtin_amdgcn_s_barrier();
  };

  for (int tt = 0; tt < 32; tt += 2) {
    TILE(tt + 0, 0);
    TILE(tt + 1, 1);
  }

  // epilogue
#pragma unroll
  for (int fm = 0; fm < 8; ++fm)
#pragma unroll
    for (int fn = 0; fn < 4; ++fn)
#pragma unroll
      for (int r = 0; r < 4; ++r) {
        int row = m0g + wm * 128 + fm * 16 + kg * 4 + r;
        int col = (nb & 3) * 256 + wn * 64 + fn * 16 + m16;
        float vv = acc[fm][fn][r] * scale;
        Cp[(size_t)row * D_ + col] = obf ? f2bf(vv) : f2h(vv);
      }
}

// ---------------------------------------------------------------- final GEMM (BT), f16 in, fp32 out
__global__ __launch_bounds__(256) void gemm_fin(const u16* __restrict__ A,
                                                const u16* __restrict__ Bw,
                                                float* __restrict__ Cp,
                                                int M, int N, int K) {
  __shared__ u16 lA[2 * 128 * 32];
  __shared__ u16 lB[2 * 128 * 32];
  const int tid  = threadIdx.x;
  const int w    = tid >> 6;
  const int lane = tid & 63;
  const int m    = lane & 15;
  const int kg   = lane >> 4;
  const int m0   = blockIdx.y * 128;
  const int n0   = blockIdx.x * 128;
  const int wm   = (w >> 1) * 64;
  const int wn   = (w & 1) * 64;
  const int rowS = tid >> 2;
  const int part = tid & 3;
  const int csrc8 = ((part ^ ((rowS >> 1) & 3))) * 8;
  const int kgs   = (kg ^ ((m >> 1) & 3)) * 8;

  floatx4 acc[4][4];
#pragma unroll
  for (int i = 0; i < 4; ++i)
#pragma unroll
    for (int j = 0; j < 4; ++j)
#pragma unroll
      for (int r = 0; r < 4; ++r) acc[i][j][r] = 0.0f;

  auto STAGE = [&](int k0, int bufsel) {
#pragma unroll
    for (int rnd = 0; rnd < 2; ++rnd) {
      const u16* ga = A  + (size_t)(m0 + rnd * 64 + rowS) * K + k0 + csrc8;
      const u16* gb = Bw + (size_t)(n0 + rnd * 64 + rowS) * K + k0 + csrc8;
      load_lds16(ga, lA + bufsel * 4096 + rnd * 2048 + w * 512);
      load_lds16(gb, lB + bufsel * 4096 + rnd * 2048 + w * 512);
    }
  };

  STAGE(0, 0);
  STAGE(32, 1);

  for (int k0 = 0; k0 < K; k0 += 32) {
    const int buf = (k0 >> 5) & 1;
    if (k0 + 32 < K) { asm volatile("s_waitcnt vmcnt(4)" ::: "memory"); }
    else             { asm volatile("s_waitcnt vmcnt(0)" ::: "memory"); }
    __builtin_amdgcn_s_barrier();
    __builtin_amdgcn_sched_barrier(0);

    const u16* pA = lA + buf * 4096;
    const u16* pB = lB + buf * 4096;
    half8 af[4], bf[4];
#pragma unroll
    for (int i = 0; i < 4; ++i) af[i] = *(const half8*)&pA[(wm + i * 16 + m) * 32 + kgs];
#pragma unroll
    for (int i = 0; i < 4; ++i) bf[i] = *(const half8*)&pB[(wn + i * 16 + m) * 32 + kgs];
#pragma unroll
    for (int mi = 0; mi < 4; ++mi)
#pragma unroll
      for (int ni = 0; ni < 4; ++ni)
        acc[mi][ni] = __builtin_amdgcn_mfma_f32_16x16x32_f16(af[mi], bf[ni], acc[mi][ni], 0, 0, 0);

    __builtin_amdgcn_sched_barrier(0);
    __builtin_amdgcn_s_barrier();
    if (k0 + 64 < K) STAGE(k0 + 64, buf);
  }

#pragma unroll
  for (int mi = 0; mi < 4; ++mi)
#pragma unroll
    for (int ni = 0; ni < 4; ++ni)
#pragma unroll
      for (int r = 0; r < 4; ++r) {
        int row = m0 + wm + mi * 16 + kg * 4 + r;
        int col = n0 + wn + ni * 16 + m;
        Cp[(size_t)row * N + col] = acc[mi][ni][r];
      }
}

// ---------------------------------------------------------------- V transpose (+key permutation), bf16
__global__ __launch_bounds__(256) void transpose_v(const u16* __restrict__ v,
                                                   u16* __restrict__ vt) {
  __shared__ u16 lds[64][72];
  const int b  = blockIdx.y >> 4;
  const int h  = blockIdx.y & 15;
  const int l0 = blockIdx.x * 64;
  const int tid = threadIdx.x;
#pragma unroll
  for (int it = 0; it < 2; ++it) {
    int idx = it * 256 + tid;
    int i = idx >> 3, off = (idx & 7) * 8;
    *(short8*)&lds[i][off] =
        *(const short8*)(v + ((size_t)(b * L_ + l0 + i)) * D_ + h * 64 + off);
  }
  __syncthreads();
  const int j  = tid >> 2;          // dh
  const int p0 = (tid & 3) * 16;
  __attribute__((aligned(16))) u16 tmp[16];
#pragma unroll
  for (int s = 0; s < 16; ++s) {
    int p = p0 + s;
    int l = (p >> 1) + ((p & 1) << 5);
    tmp[s] = lds[l][j];
  }
  u16* dst = vt + ((size_t)((b * H_ + h) * DH_ + j)) * L_ + l0 + p0;
  *(short8*)(dst)     = *(const short8*)&tmp[0];
  *(short8*)(dst + 8) = *(const short8*)&tmp[8];
}

// ---------------------------------------------------------------- fused flash attention, 32x32 MFMA
__global__ __launch_bounds__(256, 4) void attn_kernel(const u16* __restrict__ q,
                                                      const u16* __restrict__ k,
                                                      const u16* __restrict__ vt,
                                                      const float* __restrict__ biasP,
                                                      u16* __restrict__ o) {
  __shared__ u16 lK[64][72];       // f16, [key][dh]
  __shared__ u16 lVt[64][72];      // bf16, [dh][pos] (permuted keys)
  __shared__ float lRS[4][32];     // per-wave rowsum broadcast

  const int bh = blockIdx.x, qt = blockIdx.y;
  const int b = bh >> 4, h = bh & 15;
  const int tid = threadIdx.x;
  const int w = tid >> 6, lane = tid & 63;
  const int c32 = lane & 31, hi = lane >> 5;
  const int qr0 = qt * 128 + w * 32;

  const int srow  = tid >> 3;
  const int skoff = (tid & 7) * 8;

  const size_t qbase = ((size_t)((b * L_ + qr0 + c32) * H_ + h)) * DH_;
  half8 aq[4];
#pragma unroll
  for (int ks = 0; ks < 4; ++ks)
    aq[ks] = *(const half8*)(q + qbase + ks * 16 + hi * 8);

  floatx16 acc0, acc1;
#pragma unroll
  for (int i = 0; i < 16; ++i) { acc0[i] = 0.0f; acc1[i] = 0.0f; }
  float rsum0 = 0.0f, rsum1 = 0.0f;

  const u16* kp = k  + ((size_t)((b * L_ + srow) * H_ + h)) * DH_ + skoff;
  const u16* vp = vt + ((size_t)((b * H_ + h) * DH_ + srow)) * L_ + skoff;

  short8 rk[2], rv[2];
#pragma unroll
  for (int it = 0; it < 2; ++it) {
    rk[it] = *(const short8*)(kp + (size_t)it * 32 * H_ * DH_);
    rv[it] = *(const short8*)(vp + (size_t)it * 32 * L_);
  }

  const float4* bp = (const float4*)(biasP + ((size_t)(qt * 4 + w) * 16) * 2048) + lane;

  for (int c = 0; c < 16; ++c) {
    __syncthreads();
#pragma unroll
    for (int it = 0; it < 2; ++it) {
      *(short8*)&lK[it * 32 + srow][skoff]  = rk[it];
      *(short8*)&lVt[it * 32 + srow][skoff] = rv[it];
    }
    __syncthreads();

    floatx16 s0, s1;
#pragma unroll
    for (int rr = 0; rr < 4; ++rr) {
      float4 b0 = bp[rr * 64];
      float4 b1 = bp[(4 + rr) * 64];
      s0[rr * 4 + 0] = b0.x; s0[rr * 4 + 1] = b0.y; s0[rr * 4 + 2] = b0.z; s0[rr * 4 + 3] = b0.w;
      s1[rr * 4 + 0] = b1.x; s1[rr * 4 + 1] = b1.y; s1[rr * 4 + 2] = b1.z; s1[rr * 4 + 3] = b1.w;
    }
    bp += 512;

    if (c < 15) {
      kp += (size_t)64 * H_ * DH_;
      vp += 64;
#pragma unroll
      for (int it = 0; it < 2; ++it) {
        rk[it] = *(const short8*)(kp + (size_t)it * 32 * H_ * DH_);
        rv[it] = *(const short8*)(vp + (size_t)it * 32 * L_);
      }
    }

#pragma unroll
    for (int ks = 0; ks < 4; ++ks) {
      half8 bk0 = *(const half8*)&lK[c32][ks * 16 + hi * 8];
      half8 bk1 = *(const half8*)&lK[32 + c32][ks * 16 + hi * 8];
      s0 = __builtin_amdgcn_mfma_f32_32x32x16_f16(bk0, aq[ks], s0, 0, 0, 0);
      s1 = __builtin_amdgcn_mfma_f32_32x32x16_f16(bk1, aq[ks], s1, 0, 0, 0);
    }

    union { short8 v[4]; unsigned u[16]; } ap;
#pragma unroll
    for (int reg = 0; reg < 16; ++reg) {
      float p0 = EXP2(s0[reg]);
      float p1 = EXP2(s1[reg]);
      ap.u[reg] = pack_bf2(p0, p1);
      if (reg & 1) rsum1 += p0 + p1; else rsum0 += p0 + p1;
    }

#pragma unroll
    for (int ks = 0; ks < 4; ++ks) {
      short8 bv0 = *(const short8*)&lVt[c32][ks * 16 + hi * 8];
      short8 bv1 = *(const short8*)&lVt[32 + c32][ks * 16 + hi * 8];
      acc0 = __builtin_amdgcn_mfma_f32_32x32x16_bf16(ap.v[ks], bv0, acc0, 0, 0, 0);
      acc1 = __builtin_amdgcn_mfma_f32_32x32x16_bf16(ap.v[ks], bv1, acc1, 0, 0, 0);
    }
  }

  float rsum = rsum0 + rsum1;
  rsum += __shfl_xor(rsum, 32, 64);
  if (hi == 0) lRS[w][c32] = rsum;

#pragma unroll
  for (int reg = 0; reg < 16; ++reg) {
    int rl = (reg & 3) + 8 * (reg >> 2) + 4 * hi;
    float inv = 1.0f / lRS[w][rl];
    int row = qr0 + rl;
    size_t obase = ((size_t)((b * L_ + row) * H_ + h)) * DH_;
    o[obase + c32]      = f2h(acc0[reg] * inv);
    o[obase + 32 + c32] = f2h(acc1[reg] * inv);
  }
}

// ---------------------------------------------------------------- launch
extern "C" void kernel_launch(void* const* d_in, const int* in_sizes, int n_in,
                              void* d_out, int out_size, void* d_ws, size_t ws_size,
                              hipStream_t stream) {
  const float* x    = (const float*)d_in[0];
  const float* mask = (const float*)d_in[1];
  const float* Wk   = (const float*)d_in[2];
  const float* Wv   = (const float*)d_in[3];
  const float* Wq   = (const float*)d_in[4];
  const float* Wo   = (const float*)d_in[5];

  char* ws = (char*)d_ws;
  u16* xf    = (u16*)(ws);                        // 16 MB x f16 ; later attn out f16
  u16* aout  = xf;
  u16* kf    = (u16*)(ws + (16ull << 20));        // 16 MB k f16
  u16* vtb   = (u16*)(ws + (32ull << 20));        // 16 MB transposed+permuted V bf16
  float* biasP = (float*)(ws + (48ull << 20));    // 4 MB permuted bias^T (log2e-scaled)
  u16* wqf   = (u16*)(ws + (52ull << 20));        // 2 MB each, f16 weights
  u16* wkf   = (u16*)(ws + (54ull << 20));
  u16* wvf   = (u16*)(ws + (56ull << 20));
  u16* wof   = (u16*)(ws + (58ull << 20));
  u16* qf = (u16*)d_out;
  u16* vb = qf + (size_t)B_ * L_ * D_;

  cast_all<<<16384, 256, 0, stream>>>(x, Wq, Wk, Wv, Wo, mask,
                                      xf, wqf, wkf, wvf, wof, biasP);

  gemm_qkv<<<dim3(12, 32), 512, 0, stream>>>(xf, wqf, wkf, wvf, qf, kf, vb);

  transpose_v<<<dim3(L_ / 64, B_ * H_), 256, 0, stream>>>(vb, vtb);

  attn_kernel<<<dim3(B_ * H_, L_ / 128), 256, 0, stream>>>(qf, kf, vtb, biasP, aout);

  gemm_fin<<<dim3(D_ / 128, (B_ * L_) / 128), 256, 0, stream>>>(
      aout, wof, (float*)d_out, B_ * L_, D_, D_);
}

// Round 8
// 257.170 us; speedup vs baseline: 2.6886x; 2.6886x over previous
//
#include <hip/hip_runtime.h>

// Problem constants (B=8, L=1024, D=1024, H=16, DH=64)
#define B_  8
#define L_  1024
#define D_  1024
#define H_  16
#define DH_ 64

typedef unsigned short u16;
typedef __attribute__((ext_vector_type(8))) short short8;      // 8 x u16 bag (bf16)
typedef __attribute__((ext_vector_type(8))) _Float16 half8;    // 8 x f16
typedef __attribute__((ext_vector_type(4))) float floatx4;     // 16x16 C/D frag
typedef __attribute__((ext_vector_type(16))) float floatx16;   // 32x32 C/D frag

// fp32 -> bf16 round-to-nearest-even
static __device__ __forceinline__ u16 f2bf(float f) {
  union { float f; unsigned u; } cv; cv.f = f;
  unsigned u = cv.u;
  return (u16)((u + 0x7fffu + ((u >> 16) & 1u)) >> 16);
}
// fp32 -> f16 (RNE)
static __device__ __forceinline__ u16 f2h(float f) {
  union { _Float16 h; u16 u; } cv; cv.h = (_Float16)f; return cv.u;
}
// pack two fp32 -> two bf16 (round-half-up; nonneg softmax weights) via v_perm
static __device__ __forceinline__ unsigned pack_bf2(float a, float b) {
  union { float f; unsigned u; } ua, ub; ua.f = a; ub.f = b;
  return __builtin_amdgcn_perm(ub.u + 0x8000u, ua.u + 0x8000u, 0x07060302u);
}

#if __has_builtin(__builtin_amdgcn_exp2f)
#define EXP2(x) __builtin_amdgcn_exp2f(x)
#else
#define EXP2(x) __expf((x) * 0.6931471805599453f)
#endif

// ---------------------------------------------------------------- fused casts + bias permute
// blocks [0,12288): cast x/Wq/Wk/Wv/Wo fp32 -> f16
// blocks [12288,16384): permuted bias^T table, PRE-MULTIPLIED by log2(e)
__global__ void cast_all(const float* __restrict__ x,  const float* __restrict__ wq,
                         const float* __restrict__ wk, const float* __restrict__ wv,
                         const float* __restrict__ wo, const float* __restrict__ mask,
                         u16* __restrict__ xf,  u16* __restrict__ wqf,
                         u16* __restrict__ wkf, u16* __restrict__ wvf,
                         u16* __restrict__ wof, float* __restrict__ biasP) {
  int blk = blockIdx.x;
  if (blk >= 12288) {
    int i = (blk - 12288) * 256 + threadIdx.x;
    int e = i & 3, lane = (i >> 2) & 63, rr = (i >> 8) & 3, t = (i >> 10) & 1;
    int c = (i >> 11) & 15, w = (i >> 15) & 3, qt = i >> 17;
    int kk  = e + 8 * rr + 4 * (lane >> 5);
    int row = qt * 128 + w * 32 + (lane & 31);
    int key = c * 64 + t * 32 + kk;
    // log2e * ((mask-1)*1.25e8 - 24)
    biasP[i] = (mask[(size_t)row * L_ + key] - 1.0f) * 1.8033688e8f - 34.624681f;
    return;
  }
  const float* src; u16* dst; int off;
  if (blk < 8192)       { src = x;  dst = xf;  off = blk; }
  else if (blk < 9216)  { src = wq; dst = wqf; off = blk - 8192; }
  else if (blk < 10240) { src = wk; dst = wkf; off = blk - 9216; }
  else if (blk < 11264) { src = wv; dst = wvf; off = blk - 10240; }
  else                  { src = wo; dst = wof; off = blk - 11264; }
  int i = off * 1024 + threadIdx.x * 4;
  float4 f = *(const float4*)(src + i);
  ushort4 r;
  r.x = f2h(f.x); r.y = f2h(f.y); r.z = f2h(f.z); r.w = f2h(f.w);
  *(ushort4*)(dst + i) = r;
}

// ---------------------------------------------------------------- LDS staging helper
typedef __attribute__((address_space(3))) void  lds_void;
typedef const __attribute__((address_space(1))) void g_void;
static __device__ __forceinline__ void load_lds16(const void* g, void* l) {
  __builtin_amdgcn_global_load_lds((g_void*)g, (lds_void*)l, 16, 0, 0);
}

// ---------------------------------------------------------------- fused QKV GEMM (BT), f16 inputs
// grid (24, 64): n-blocks 0-7 -> q (scale 1/8*log2e, f16), 8-15 -> k (f16), 16-23 -> v (bf16)
// Round-5 proven version: LDS double-buffered BK=32 tiles, counted vmcnt(4),
// chunk-XOR swizzle (PMC-verified 0 bank conflicts). 682 TF.
__global__ __launch_bounds__(256) void gemm_qkv(const u16* __restrict__ A,
                                                const u16* __restrict__ wq,
                                                const u16* __restrict__ wk,
                                                const u16* __restrict__ wv,
                                                u16* __restrict__ qf,
                                                u16* __restrict__ kf,
                                                u16* __restrict__ vb) {
  const int K = D_, N = D_;
  int nb = blockIdx.x;
  const u16* Bw; u16* Cp; float scale; int obf;
  if (nb < 8)       { Bw = wq; Cp = qf; scale = 0.18033688f; obf = 0; }  // 0.125*log2e
  else if (nb < 16) { Bw = wk; Cp = kf; scale = 1.0f;        obf = 0; }
  else              { Bw = wv; Cp = vb; scale = 1.0f;        obf = 1; }
  const int n0 = (nb & 7) * 128;

  __shared__ u16 lA[2 * 128 * 32];   // double-buffered A tile
  __shared__ u16 lB[2 * 128 * 32];   // double-buffered B tile
  const int tid  = threadIdx.x;
  const int w    = tid >> 6;
  const int lane = tid & 63;
  const int m    = lane & 15;
  const int kg   = lane >> 4;
  const int m0   = blockIdx.y * 128;
  const int wm   = (w >> 1) * 64;
  const int wn   = (w & 1) * 64;
  const int rowS = tid >> 2;
  const int part = tid & 3;
  // swizzle: stored chunk c' holds global chunk c' ^ ((row>>1)&3)
  const int csrc8 = ((part ^ ((rowS >> 1) & 3))) * 8;   // staging source column
  const int kgs   = (kg ^ ((m >> 1) & 3)) * 8;          // fragment read column

  floatx4 acc[4][4];
#pragma unroll
  for (int i = 0; i < 4; ++i)
#pragma unroll
    for (int j = 0; j < 4; ++j)
#pragma unroll
      for (int r = 0; r < 4; ++r) acc[i][j][r] = 0.0f;

  auto STAGE = [&](int k0, int bufsel) {
#pragma unroll
    for (int rnd = 0; rnd < 2; ++rnd) {
      const u16* ga = A  + (size_t)(m0 + rnd * 64 + rowS) * K + k0 + csrc8;
      const u16* gb = Bw + (size_t)(n0 + rnd * 64 + rowS) * K + k0 + csrc8;
      load_lds16(ga, lA + bufsel * 4096 + rnd * 2048 + w * 512);
      load_lds16(gb, lB + bufsel * 4096 + rnd * 2048 + w * 512);
    }
  };

  STAGE(0, 0);
  STAGE(32, 1);

  for (int k0 = 0; k0 < K; k0 += 32) {
    const int buf = (k0 >> 5) & 1;
    if (k0 + 32 < K) { asm volatile("s_waitcnt vmcnt(4)" ::: "memory"); }
    else             { asm volatile("s_waitcnt vmcnt(0)" ::: "memory"); }
    __builtin_amdgcn_s_barrier();
    __builtin_amdgcn_sched_barrier(0);

    const u16* pA = lA + buf * 4096;
    const u16* pB = lB + buf * 4096;
    half8 af[4], bf[4];
#pragma unroll
    for (int i = 0; i < 4; ++i) af[i] = *(const half8*)&pA[(wm + i * 16 + m) * 32 + kgs];
#pragma unroll
    for (int i = 0; i < 4; ++i) bf[i] = *(const half8*)&pB[(wn + i * 16 + m) * 32 + kgs];
#pragma unroll
    for (int mi = 0; mi < 4; ++mi)
#pragma unroll
      for (int ni = 0; ni < 4; ++ni)
        acc[mi][ni] = __builtin_amdgcn_mfma_f32_16x16x32_f16(af[mi], bf[ni], acc[mi][ni], 0, 0, 0);

    __builtin_amdgcn_sched_barrier(0);
    __builtin_amdgcn_s_barrier();
    if (k0 + 64 < K) STAGE(k0 + 64, buf);
  }

#pragma unroll
  for (int mi = 0; mi < 4; ++mi)
#pragma unroll
    for (int ni = 0; ni < 4; ++ni)
#pragma unroll
      for (int r = 0; r < 4; ++r) {
        int row = m0 + wm + mi * 16 + kg * 4 + r;
        int col = n0 + wn + ni * 16 + m;
        size_t idx = (size_t)row * N + col;
        float vv = acc[mi][ni][r] * scale;
        Cp[idx] = obf ? f2bf(vv) : f2h(vv);
      }
}

// ---------------------------------------------------------------- final GEMM (BT), f16 in, fp32 out
__global__ __launch_bounds__(256) void gemm_fin(const u16* __restrict__ A,
                                                const u16* __restrict__ Bw,
                                                float* __restrict__ Cp,
                                                int M, int N, int K) {
  __shared__ u16 lA[2 * 128 * 32];
  __shared__ u16 lB[2 * 128 * 32];
  const int tid  = threadIdx.x;
  const int w    = tid >> 6;
  const int lane = tid & 63;
  const int m    = lane & 15;
  const int kg   = lane >> 4;
  const int m0   = blockIdx.y * 128;
  const int n0   = blockIdx.x * 128;
  const int wm   = (w >> 1) * 64;
  const int wn   = (w & 1) * 64;
  const int rowS = tid >> 2;
  const int part = tid & 3;
  const int csrc8 = ((part ^ ((rowS >> 1) & 3))) * 8;
  const int kgs   = (kg ^ ((m >> 1) & 3)) * 8;

  floatx4 acc[4][4];
#pragma unroll
  for (int i = 0; i < 4; ++i)
#pragma unroll
    for (int j = 0; j < 4; ++j)
#pragma unroll
      for (int r = 0; r < 4; ++r) acc[i][j][r] = 0.0f;

  auto STAGE = [&](int k0, int bufsel) {
#pragma unroll
    for (int rnd = 0; rnd < 2; ++rnd) {
      const u16* ga = A  + (size_t)(m0 + rnd * 64 + rowS) * K + k0 + csrc8;
      const u16* gb = Bw + (size_t)(n0 + rnd * 64 + rowS) * K + k0 + csrc8;
      load_lds16(ga, lA + bufsel * 4096 + rnd * 2048 + w * 512);
      load_lds16(gb, lB + bufsel * 4096 + rnd * 2048 + w * 512);
    }
  };

  STAGE(0, 0);
  STAGE(32, 1);

  for (int k0 = 0; k0 < K; k0 += 32) {
    const int buf = (k0 >> 5) & 1;
    if (k0 + 32 < K) { asm volatile("s_waitcnt vmcnt(4)" ::: "memory"); }
    else             { asm volatile("s_waitcnt vmcnt(0)" ::: "memory"); }
    __builtin_amdgcn_s_barrier();
    __builtin_amdgcn_sched_barrier(0);

    const u16* pA = lA + buf * 4096;
    const u16* pB = lB + buf * 4096;
    half8 af[4], bf[4];
#pragma unroll
    for (int i = 0; i < 4; ++i) af[i] = *(const half8*)&pA[(wm + i * 16 + m) * 32 + kgs];
#pragma unroll
    for (int i = 0; i < 4; ++i) bf[i] = *(const half8*)&pB[(wn + i * 16 + m) * 32 + kgs];
#pragma unroll
    for (int mi = 0; mi < 4; ++mi)
#pragma unroll
      for (int ni = 0; ni < 4; ++ni)
        acc[mi][ni] = __builtin_amdgcn_mfma_f32_16x16x32_f16(af[mi], bf[ni], acc[mi][ni], 0, 0, 0);

    __builtin_amdgcn_sched_barrier(0);
    __builtin_amdgcn_s_barrier();
    if (k0 + 64 < K) STAGE(k0 + 64, buf);
  }

#pragma unroll
  for (int mi = 0; mi < 4; ++mi)
#pragma unroll
    for (int ni = 0; ni < 4; ++ni)
#pragma unroll
      for (int r = 0; r < 4; ++r) {
        int row = m0 + wm + mi * 16 + kg * 4 + r;
        int col = n0 + wn + ni * 16 + m;
        Cp[(size_t)row * N + col] = acc[mi][ni][r];
      }
}

// ---------------------------------------------------------------- V transpose (+key permutation), bf16
__global__ __launch_bounds__(256) void transpose_v(const u16* __restrict__ v,
                                                   u16* __restrict__ vt) {
  __shared__ u16 lds[64][72];
  const int b  = blockIdx.y >> 4;
  const int h  = blockIdx.y & 15;
  const int l0 = blockIdx.x * 64;
  const int tid = threadIdx.x;
#pragma unroll
  for (int it = 0; it < 2; ++it) {
    int idx = it * 256 + tid;
    int i = idx >> 3, off = (idx & 7) * 8;
    *(short8*)&lds[i][off] =
        *(const short8*)(v + ((size_t)(b * L_ + l0 + i)) * D_ + h * 64 + off);
  }
  __syncthreads();
  const int j  = tid >> 2;          // dh
  const int p0 = (tid & 3) * 16;
  __attribute__((aligned(16))) u16 tmp[16];
#pragma unroll
  for (int s = 0; s < 16; ++s) {
    int p = p0 + s;
    int l = (p >> 1) + ((p & 1) << 5);
    tmp[s] = lds[l][j];
  }
  u16* dst = vt + ((size_t)((b * H_ + h) * DH_ + j)) * L_ + l0 + p0;
  *(short8*)(dst)     = *(const short8*)&tmp[0];
  *(short8*)(dst + 8) = *(const short8*)&tmp[8];
}

// ---------------------------------------------------------------- fused flash attention, 32x32 MFMA
// grid (bh=128, qt=8). 4 waves x 32 q-rows = 128 rows/block. 64-key chunks.
//
// Double-buffered K/V LDS, ONE barrier per chunk (was 2):
//   iter c: ds_write chunk c+1 -> buf^1  (prev iter's trailing barrier
//           separates these writes from chunk c-1's readers of buf^1)
//           issue global prefetch of chunk c+2
//           compute chunk c from buf (S-MFMA overlaps the ds_writes)
//           __syncthreads()
// Register-diet (<=128 regs, 4 waves/SIMD); LDS 37.4 KB -> still 4 blocks/CU.
__global__ __launch_bounds__(256, 4) void attn_kernel(const u16* __restrict__ q,
                                                      const u16* __restrict__ k,
                                                      const u16* __restrict__ vt,
                                                      const float* __restrict__ biasP,
                                                      u16* __restrict__ o) {
  __shared__ u16 lK[2][64][72];    // f16, [key][dh]
  __shared__ u16 lVt[2][64][72];   // bf16, [dh][pos] (permuted keys)
  __shared__ float lRS[4][32];     // per-wave rowsum broadcast

  const int bh = blockIdx.x, qt = blockIdx.y;
  const int b = bh >> 4, h = bh & 15;
  const int tid = threadIdx.x;
  const int w = tid >> 6, lane = tid & 63;
  const int c32 = lane & 31, hi = lane >> 5;
  const int qr0 = qt * 128 + w * 32;

  const int srow  = tid >> 3;      // 0..31 (stages 2 rows via it)
  const int skoff = (tid & 7) * 8;

  // Q B-frags: lane holds Q[q=qr0+c32][dh-slice ks*16+hi*8]
  const size_t qbase = ((size_t)((b * L_ + qr0 + c32) * H_ + h)) * DH_;
  half8 aq[4];
#pragma unroll
  for (int ks = 0; ks < 4; ++ks)
    aq[ks] = *(const half8*)(q + qbase + ks * 16 + hi * 8);

  floatx16 acc0, acc1;
#pragma unroll
  for (int i = 0; i < 16; ++i) { acc0[i] = 0.0f; acc1[i] = 0.0f; }
  float rsum0 = 0.0f, rsum1 = 0.0f;

  // staging pointers, advanced by constant stride per chunk
  const u16* kp = k  + ((size_t)((b * L_ + srow) * H_ + h)) * DH_ + skoff;
  const u16* vp = vt + ((size_t)((b * H_ + h) * DH_ + srow)) * L_ + skoff;

  short8 rk[2], rv[2];
  // chunk 0 -> regs -> buf 0
#pragma unroll
  for (int it = 0; it < 2; ++it) {
    rk[it] = *(const short8*)(kp + (size_t)it * 32 * H_ * DH_);
    rv[it] = *(const short8*)(vp + (size_t)it * 32 * L_);
  }
#pragma unroll
  for (int it = 0; it < 2; ++it) {
    *(short8*)&lK[0][it * 32 + srow][skoff]  = rk[it];
    *(short8*)&lVt[0][it * 32 + srow][skoff] = rv[it];
  }
  // chunk 1 -> regs
  kp += (size_t)64 * H_ * DH_;
  vp += 64;
#pragma unroll
  for (int it = 0; it < 2; ++it) {
    rk[it] = *(const short8*)(kp + (size_t)it * 32 * H_ * DH_);
    rv[it] = *(const short8*)(vp + (size_t)it * 32 * L_);
  }
  __syncthreads();

  const float4* bp = (const float4*)(biasP + ((size_t)(qt * 4 + w) * 16) * 2048) + lane;

  for (int c = 0; c < 16; ++c) {
    const int buf = c & 1;
    // write chunk c+1 (held in rk/rv) into the other buffer
    if (c < 15) {
#pragma unroll
      for (int it = 0; it < 2; ++it) {
        *(short8*)&lK[buf ^ 1][it * 32 + srow][skoff]  = rk[it];
        *(short8*)&lVt[buf ^ 1][it * 32 + srow][skoff] = rv[it];
      }
    }
    // issue global prefetch of chunk c+2
    if (c < 14) {
      kp += (size_t)64 * H_ * DH_;
      vp += 64;
#pragma unroll
      for (int it = 0; it < 2; ++it) {
        rk[it] = *(const short8*)(kp + (size_t)it * 32 * H_ * DH_);
        rv[it] = *(const short8*)(vp + (size_t)it * 32 * L_);
      }
    }

    // S^T tiles: bias^T as accumulator init, loaded at use
    floatx16 s0, s1;
#pragma unroll
    for (int rr = 0; rr < 4; ++rr) {
      float4 b0 = bp[rr * 64];
      float4 b1 = bp[(4 + rr) * 64];
      s0[rr * 4 + 0] = b0.x; s0[rr * 4 + 1] = b0.y; s0[rr * 4 + 2] = b0.z; s0[rr * 4 + 3] = b0.w;
      s1[rr * 4 + 0] = b1.x; s1[rr * 4 + 1] = b1.y; s1[rr * 4 + 2] = b1.z; s1[rr * 4 + 3] = b1.w;
    }
    bp += 512;

#pragma unroll
    for (int ks = 0; ks < 4; ++ks) {
      half8 bk0 = *(const half8*)&lK[buf][c32][ks * 16 + hi * 8];
      half8 bk1 = *(const half8*)&lK[buf][32 + c32][ks * 16 + hi * 8];
      s0 = __builtin_amdgcn_mfma_f32_32x32x16_f16(bk0, aq[ks], s0, 0, 0, 0);
      s1 = __builtin_amdgcn_mfma_f32_32x32x16_f16(bk1, aq[ks], s1, 0, 0, 0);
    }

    // softmax weights (exp2; shift folded into bias) -> in-register bf16 PV A-frags
    union { short8 v[4]; unsigned u[16]; } ap;
#pragma unroll
    for (int reg = 0; reg < 16; ++reg) {
      float p0 = EXP2(s0[reg]);
      float p1 = EXP2(s1[reg]);
      ap.u[reg] = pack_bf2(p0, p1);
      if (reg & 1) rsum1 += p0 + p1; else rsum0 += p0 + p1;
    }

    // O += P V (2 dh-tiles), bf16
#pragma unroll
    for (int ks = 0; ks < 4; ++ks) {
      short8 bv0 = *(const short8*)&lVt[buf][c32][ks * 16 + hi * 8];
      short8 bv1 = *(const short8*)&lVt[buf][32 + c32][ks * 16 + hi * 8];
      acc0 = __builtin_amdgcn_mfma_f32_32x32x16_bf16(ap.v[ks], bv0, acc0, 0, 0, 0);
      acc1 = __builtin_amdgcn_mfma_f32_32x32x16_bf16(ap.v[ks], bv1, acc1, 0, 0, 0);
    }

    __syncthreads();               // buf^1 fully written; buf free for overwrite
  }

  // rowsum: combine hi halves, broadcast via wave-private LDS.
  float rsum = rsum0 + rsum1;
  rsum += __shfl_xor(rsum, 32, 64);
  if (hi == 0) lRS[w][c32] = rsum;

  // epilogue: normalize (acc C-layout: row=(reg&3)+8*(reg>>2)+4*hi, col=dh=c32)
#pragma unroll
  for (int reg = 0; reg < 16; ++reg) {
    int rl = (reg & 3) + 8 * (reg >> 2) + 4 * hi;
    float inv = 1.0f / lRS[w][rl];
    int row = qr0 + rl;
    size_t obase = ((size_t)((b * L_ + row) * H_ + h)) * DH_;
    o[obase + c32]      = f2h(acc0[reg] * inv);
    o[obase + 32 + c32] = f2h(acc1[reg] * inv);
  }
}

// ---------------------------------------------------------------- launch
extern "C" void kernel_launch(void* const* d_in, const int* in_sizes, int n_in,
                              void* d_out, int out_size, void* d_ws, size_t ws_size,
                              hipStream_t stream) {
  const float* x    = (const float*)d_in[0];
  const float* mask = (const float*)d_in[1];
  const float* Wk   = (const float*)d_in[2];
  const float* Wv   = (const float*)d_in[3];
  const float* Wq   = (const float*)d_in[4];
  const float* Wo   = (const float*)d_in[5];

  char* ws = (char*)d_ws;
  u16* xf    = (u16*)(ws);                        // 16 MB x f16 ; later attn out f16
  u16* aout  = xf;
  u16* kf    = (u16*)(ws + (16ull << 20));        // 16 MB k f16
  u16* vtb   = (u16*)(ws + (32ull << 20));        // 16 MB transposed+permuted V bf16
  float* biasP = (float*)(ws + (48ull << 20));    // 4 MB permuted bias^T (log2e-scaled)
  u16* wqf   = (u16*)(ws + (52ull << 20));        // 2 MB each, f16 weights
  u16* wkf   = (u16*)(ws + (54ull << 20));
  u16* wvf   = (u16*)(ws + (56ull << 20));
  u16* wof   = (u16*)(ws + (58ull << 20));
  u16* qf = (u16*)d_out;
  u16* vb = qf + (size_t)B_ * L_ * D_;

  cast_all<<<16384, 256, 0, stream>>>(x, Wq, Wk, Wv, Wo, mask,
                                      xf, wqf, wkf, wvf, wof, biasP);

  gemm_qkv<<<dim3(24, 64), 256, 0, stream>>>(xf, wqf, wkf, wvf, qf, kf, vb);

  transpose_v<<<dim3(L_ / 64, B_ * H_), 256, 0, stream>>>(vb, vtb);

  attn_kernel<<<dim3(B_ * H_, L_ / 128), 256, 0, stream>>>(qf, kf, vtb, biasP, aout);

  gemm_fin<<<dim3(D_ / 128, (B_ * L_) / 128), 256, 0, stream>>>(
      aout, wof, (float*)d_out, B_ * L_, D_, D_);
}

// Round 9
// 253.418 us; speedup vs baseline: 2.7284x; 1.0148x over previous
//
#include <hip/hip_runtime.h>

// Problem constants (B=8, L=1024, D=1024, H=16, DH=64)
#define B_  8
#define L_  1024
#define D_  1024
#define H_  16
#define DH_ 64

typedef unsigned short u16;
typedef __attribute__((ext_vector_type(8))) short short8;      // 8 x u16 bag (bf16)
typedef __attribute__((ext_vector_type(8))) _Float16 half8;    // 8 x f16
typedef __attribute__((ext_vector_type(4))) float floatx4;     // 16x16 C/D frag
typedef __attribute__((ext_vector_type(16))) float floatx16;   // 32x32 C/D frag

// fp32 -> bf16 round-to-nearest-even
static __device__ __forceinline__ u16 f2bf(float f) {
  union { float f; unsigned u; } cv; cv.f = f;
  unsigned u = cv.u;
  return (u16)((u + 0x7fffu + ((u >> 16) & 1u)) >> 16);
}
// fp32 -> f16 (RNE)
static __device__ __forceinline__ u16 f2h(float f) {
  union { _Float16 h; u16 u; } cv; cv.h = (_Float16)f; return cv.u;
}
// pack two fp32 -> two bf16 (round-half-up; nonneg softmax weights) via v_perm
static __device__ __forceinline__ unsigned pack_bf2(float a, float b) {
  union { float f; unsigned u; } ua, ub; ua.f = a; ub.f = b;
  return __builtin_amdgcn_perm(ub.u + 0x8000u, ua.u + 0x8000u, 0x07060302u);
}

#if __has_builtin(__builtin_amdgcn_exp2f)
#define EXP2(x) __builtin_amdgcn_exp2f(x)
#else
#define EXP2(x) __expf((x) * 0.6931471805599453f)
#endif

// ---------------------------------------------------------------- fused casts + bias permute
// blocks [0,12288): cast x/Wq/Wk/Wv/Wo fp32 -> f16
// blocks [12288,16384): permuted bias^T table, PRE-MULTIPLIED by log2(e)
__global__ void cast_all(const float* __restrict__ x,  const float* __restrict__ wq,
                         const float* __restrict__ wk, const float* __restrict__ wv,
                         const float* __restrict__ wo, const float* __restrict__ mask,
                         u16* __restrict__ xf,  u16* __restrict__ wqf,
                         u16* __restrict__ wkf, u16* __restrict__ wvf,
                         u16* __restrict__ wof, float* __restrict__ biasP) {
  int blk = blockIdx.x;
  if (blk >= 12288) {
    int i = (blk - 12288) * 256 + threadIdx.x;
    int e = i & 3, lane = (i >> 2) & 63, rr = (i >> 8) & 3, t = (i >> 10) & 1;
    int c = (i >> 11) & 15, w = (i >> 15) & 3, qt = i >> 17;
    int kk  = e + 8 * rr + 4 * (lane >> 5);
    int row = qt * 128 + w * 32 + (lane & 31);
    int key = c * 64 + t * 32 + kk;
    // log2e * ((mask-1)*1.25e8 - 24)
    biasP[i] = (mask[(size_t)row * L_ + key] - 1.0f) * 1.8033688e8f - 34.624681f;
    return;
  }
  const float* src; u16* dst; int off;
  if (blk < 8192)       { src = x;  dst = xf;  off = blk; }
  else if (blk < 9216)  { src = wq; dst = wqf; off = blk - 8192; }
  else if (blk < 10240) { src = wk; dst = wkf; off = blk - 9216; }
  else if (blk < 11264) { src = wv; dst = wvf; off = blk - 10240; }
  else                  { src = wo; dst = wof; off = blk - 11264; }
  int i = off * 1024 + threadIdx.x * 4;
  float4 f = *(const float4*)(src + i);
  ushort4 r;
  r.x = f2h(f.x); r.y = f2h(f.y); r.z = f2h(f.z); r.w = f2h(f.w);
  *(ushort4*)(dst + i) = r;
}

// ---------------------------------------------------------------- LDS staging helper
typedef __attribute__((address_space(3))) void  lds_void;
typedef const __attribute__((address_space(1))) void g_void;
static __device__ __forceinline__ void load_lds16(const void* g, void* l) {
  __builtin_amdgcn_global_load_lds((g_void*)g, (lds_void*)l, 16, 0, 0);
}

// ---------------------------------------------------------------- fused QKV GEMM (BT), f16 inputs
// grid (24, 64): n-blocks 0-7 -> q (scale 1/8*log2e, f16), 8-15 -> k (f16),
// 16-23 -> v (bf16, written DIRECTLY in transposed+key-permuted vt layout:
// vt[(b*H+h)*DH+dh][l-chunk base + pos], pos = 2*(l&31)+((l>>5)&1) -- the
// transpose_v kernel is fused into this epilogue via an LDS roundtrip).
// K-loop: LDS double-buffered BK=32 tiles, counted vmcnt(4), chunk-XOR swizzle
// (PMC-verified 0 bank conflicts). 682 TF.
__global__ __launch_bounds__(256) void gemm_qkv(const u16* __restrict__ A,
                                                const u16* __restrict__ wq,
                                                const u16* __restrict__ wk,
                                                const u16* __restrict__ wv,
                                                u16* __restrict__ qf,
                                                u16* __restrict__ kf,
                                                u16* __restrict__ vt) {
  const int K = D_, N = D_;
  int nb = blockIdx.x;
  const u16* Bw; u16* Cp; float scale; int obf;
  if (nb < 8)       { Bw = wq; Cp = qf; scale = 0.18033688f; obf = 0; }  // 0.125*log2e
  else if (nb < 16) { Bw = wk; Cp = kf; scale = 1.0f;        obf = 0; }
  else              { Bw = wv; Cp = vt; scale = 1.0f;        obf = 1; }
  const int n0 = (nb & 7) * 128;

  __shared__ u16 lAB[16384];         // lA (8192) | lB (8192); reused as 128x128 tbuf
  u16* lA = lAB;
  u16* lB = lAB + 8192;
  const int tid  = threadIdx.x;
  const int w    = tid >> 6;
  const int lane = tid & 63;
  const int m    = lane & 15;
  const int kg   = lane >> 4;
  const int m0   = blockIdx.y * 128;
  const int wm   = (w >> 1) * 64;
  const int wn   = (w & 1) * 64;
  const int rowS = tid >> 2;
  const int part = tid & 3;
  // swizzle: stored chunk c' holds global chunk c' ^ ((row>>1)&3)
  const int csrc8 = ((part ^ ((rowS >> 1) & 3))) * 8;   // staging source column
  const int kgs   = (kg ^ ((m >> 1) & 3)) * 8;          // fragment read column

  floatx4 acc[4][4];
#pragma unroll
  for (int i = 0; i < 4; ++i)
#pragma unroll
    for (int j = 0; j < 4; ++j)
#pragma unroll
      for (int r = 0; r < 4; ++r) acc[i][j][r] = 0.0f;

  auto STAGE = [&](int k0, int bufsel) {
#pragma unroll
    for (int rnd = 0; rnd < 2; ++rnd) {
      const u16* ga = A  + (size_t)(m0 + rnd * 64 + rowS) * K + k0 + csrc8;
      const u16* gb = Bw + (size_t)(n0 + rnd * 64 + rowS) * K + k0 + csrc8;
      load_lds16(ga, lA + bufsel * 4096 + rnd * 2048 + w * 512);
      load_lds16(gb, lB + bufsel * 4096 + rnd * 2048 + w * 512);
    }
  };

  STAGE(0, 0);
  STAGE(32, 1);

  for (int k0 = 0; k0 < K; k0 += 32) {
    const int buf = (k0 >> 5) & 1;
    if (k0 + 32 < K) { asm volatile("s_waitcnt vmcnt(4)" ::: "memory"); }
    else             { asm volatile("s_waitcnt vmcnt(0)" ::: "memory"); }
    __builtin_amdgcn_s_barrier();
    __builtin_amdgcn_sched_barrier(0);

    const u16* pA = lA + buf * 4096;
    const u16* pB = lB + buf * 4096;
    half8 af[4], bf[4];
#pragma unroll
    for (int i = 0; i < 4; ++i) af[i] = *(const half8*)&pA[(wm + i * 16 + m) * 32 + kgs];
#pragma unroll
    for (int i = 0; i < 4; ++i) bf[i] = *(const half8*)&pB[(wn + i * 16 + m) * 32 + kgs];
#pragma unroll
    for (int mi = 0; mi < 4; ++mi)
#pragma unroll
      for (int ni = 0; ni < 4; ++ni)
        acc[mi][ni] = __builtin_amdgcn_mfma_f32_16x16x32_f16(af[mi], bf[ni], acc[mi][ni], 0, 0, 0);

    __builtin_amdgcn_sched_barrier(0);
    __builtin_amdgcn_s_barrier();
    if (k0 + 64 < K) STAGE(k0 + 64, buf);
  }

  if (!obf) {
    // q/k: normal f16 store
#pragma unroll
    for (int mi = 0; mi < 4; ++mi)
#pragma unroll
      for (int ni = 0; ni < 4; ++ni)
#pragma unroll
        for (int r = 0; r < 4; ++r) {
          int row = m0 + wm + mi * 16 + kg * 4 + r;
          int col = n0 + wn + ni * 16 + m;
          Cp[(size_t)row * N + col] = f2h(acc[mi][ni][r] * scale);
        }
  } else {
    // V: bf16 tile -> LDS (row-major 128x128) -> transposed+permuted store to vt.
    // After the K-loop's final barrier all LDS reads have completed (they fed
    // the last MFMAs before that barrier), so lAB is free to overwrite.
#pragma unroll
    for (int mi = 0; mi < 4; ++mi)
#pragma unroll
      for (int ni = 0; ni < 4; ++ni)
#pragma unroll
        for (int r = 0; r < 4; ++r) {
          int rl = wm + mi * 16 + kg * 4 + r;      // 0..127 local row (l - m0)
          int cl = wn + ni * 16 + m;               // 0..127 local col (e - n0)
          lAB[rl * 128 + cl] = f2bf(acc[mi][ni][r]);
        }
    __syncthreads();
    const int b  = m0 >> 10;                       // batch of this 128-row strip
    const int l0 = m0 & 1023;                      // row offset within sequence
    const int h0 = (nb & 7) * 2;                   // first head of this col strip
    const int j  = tid >> 2;                       // dh (0..63)
    const int p0 = (tid & 3) * 16;                 // position base
#pragma unroll
    for (int hh = 0; hh < 2; ++hh) {
#pragma unroll
      for (int cc = 0; cc < 2; ++cc) {
        __attribute__((aligned(16))) u16 tmp[16];
#pragma unroll
        for (int s = 0; s < 16; ++s) {
          int p   = p0 + s;
          int l64 = (p >> 1) + ((p & 1) << 5);     // key within 64-chunk at pos p
          tmp[s] = lAB[(cc * 64 + l64) * 128 + hh * 64 + j];
        }
        u16* dst = vt + ((size_t)((b * H_ + h0 + hh) * DH_ + j)) * L_ + l0 + cc * 64 + p0;
        *(short8*)(dst)     = *(const short8*)&tmp[0];
        *(short8*)(dst + 8) = *(const short8*)&tmp[8];
      }
    }
  }
}

// ---------------------------------------------------------------- final GEMM (BT), f16 in, fp32 out
__global__ __launch_bounds__(256) void gemm_fin(const u16* __restrict__ A,
                                                const u16* __restrict__ Bw,
                                                float* __restrict__ Cp,
                                                int M, int N, int K) {
  __shared__ u16 lA[2 * 128 * 32];
  __shared__ u16 lB[2 * 128 * 32];
  const int tid  = threadIdx.x;
  const int w    = tid >> 6;
  const int lane = tid & 63;
  const int m    = lane & 15;
  const int kg   = lane >> 4;
  const int m0   = blockIdx.y * 128;
  const int n0   = blockIdx.x * 128;
  const int wm   = (w >> 1) * 64;
  const int wn   = (w & 1) * 64;
  const int rowS = tid >> 2;
  const int part = tid & 3;
  const int csrc8 = ((part ^ ((rowS >> 1) & 3))) * 8;
  const int kgs   = (kg ^ ((m >> 1) & 3)) * 8;

  floatx4 acc[4][4];
#pragma unroll
  for (int i = 0; i < 4; ++i)
#pragma unroll
    for (int j = 0; j < 4; ++j)
#pragma unroll
      for (int r = 0; r < 4; ++r) acc[i][j][r] = 0.0f;

  auto STAGE = [&](int k0, int bufsel) {
#pragma unroll
    for (int rnd = 0; rnd < 2; ++rnd) {
      const u16* ga = A  + (size_t)(m0 + rnd * 64 + rowS) * K + k0 + csrc8;
      const u16* gb = Bw + (size_t)(n0 + rnd * 64 + rowS) * K + k0 + csrc8;
      load_lds16(ga, lA + bufsel * 4096 + rnd * 2048 + w * 512);
      load_lds16(gb, lB + bufsel * 4096 + rnd * 2048 + w * 512);
    }
  };

  STAGE(0, 0);
  STAGE(32, 1);

  for (int k0 = 0; k0 < K; k0 += 32) {
    const int buf = (k0 >> 5) & 1;
    if (k0 + 32 < K) { asm volatile("s_waitcnt vmcnt(4)" ::: "memory"); }
    else             { asm volatile("s_waitcnt vmcnt(0)" ::: "memory"); }
    __builtin_amdgcn_s_barrier();
    __builtin_amdgcn_sched_barrier(0);

    const u16* pA = lA + buf * 4096;
    const u16* pB = lB + buf * 4096;
    half8 af[4], bf[4];
#pragma unroll
    for (int i = 0; i < 4; ++i) af[i] = *(const half8*)&pA[(wm + i * 16 + m) * 32 + kgs];
#pragma unroll
    for (int i = 0; i < 4; ++i) bf[i] = *(const half8*)&pB[(wn + i * 16 + m) * 32 + kgs];
#pragma unroll
    for (int mi = 0; mi < 4; ++mi)
#pragma unroll
      for (int ni = 0; ni < 4; ++ni)
        acc[mi][ni] = __builtin_amdgcn_mfma_f32_16x16x32_f16(af[mi], bf[ni], acc[mi][ni], 0, 0, 0);

    __builtin_amdgcn_sched_barrier(0);
    __builtin_amdgcn_s_barrier();
    if (k0 + 64 < K) STAGE(k0 + 64, buf);
  }

#pragma unroll
  for (int mi = 0; mi < 4; ++mi)
#pragma unroll
    for (int ni = 0; ni < 4; ++ni)
#pragma unroll
      for (int r = 0; r < 4; ++r) {
        int row = m0 + wm + mi * 16 + kg * 4 + r;
        int col = n0 + wn + ni * 16 + m;
        Cp[(size_t)row * N + col] = acc[mi][ni][r];
      }
}

// ---------------------------------------------------------------- fused flash attention, 32x32 MFMA
// grid (bh=128, qt=8). 4 waves x 32 q-rows = 128 rows/block. 64-key chunks.
// Round-4 proven version (register diet, <=128 regs, 4 waves/SIMD).
__global__ __launch_bounds__(256, 4) void attn_kernel(const u16* __restrict__ q,
                                                      const u16* __restrict__ k,
                                                      const u16* __restrict__ vt,
                                                      const float* __restrict__ biasP,
                                                      u16* __restrict__ o) {
  __shared__ u16 lK[64][72];       // f16, [key][dh]
  __shared__ u16 lVt[64][72];      // bf16, [dh][pos] (permuted keys)
  __shared__ float lRS[4][32];     // per-wave rowsum broadcast

  const int bh = blockIdx.x, qt = blockIdx.y;
  const int b = bh >> 4, h = bh & 15;
  const int tid = threadIdx.x;
  const int w = tid >> 6, lane = tid & 63;
  const int c32 = lane & 31, hi = lane >> 5;
  const int qr0 = qt * 128 + w * 32;

  const int srow  = tid >> 3;      // 0..31 (stages 2 rows via it)
  const int skoff = (tid & 7) * 8;

  // Q B-frags: lane holds Q[q=qr0+c32][dh-slice ks*16+hi*8]
  const size_t qbase = ((size_t)((b * L_ + qr0 + c32) * H_ + h)) * DH_;
  half8 aq[4];
#pragma unroll
  for (int ks = 0; ks < 4; ++ks)
    aq[ks] = *(const half8*)(q + qbase + ks * 16 + hi * 8);

  floatx16 acc0, acc1;
#pragma unroll
  for (int i = 0; i < 16; ++i) { acc0[i] = 0.0f; acc1[i] = 0.0f; }
  float rsum0 = 0.0f, rsum1 = 0.0f;

  // staging pointers (chunk 0), advanced by constant stride per chunk
  const u16* kp = k  + ((size_t)((b * L_ + srow) * H_ + h)) * DH_ + skoff;
  const u16* vp = vt + ((size_t)((b * H_ + h) * DH_ + srow)) * L_ + skoff;

  short8 rk[2], rv[2];             // chunk-0 K/V prefetch
#pragma unroll
  for (int it = 0; it < 2; ++it) {
    rk[it] = *(const short8*)(kp + (size_t)it * 32 * H_ * DH_);
    rv[it] = *(const short8*)(vp + (size_t)it * 32 * L_);
  }

  const float4* bp = (const float4*)(biasP + ((size_t)(qt * 4 + w) * 16) * 2048) + lane;

  for (int c = 0; c < 16; ++c) {
    __syncthreads();               // previous chunk readers done
#pragma unroll
    for (int it = 0; it < 2; ++it) {
      *(short8*)&lK[it * 32 + srow][skoff]  = rk[it];
      *(short8*)&lVt[it * 32 + srow][skoff] = rv[it];
    }
    __syncthreads();

    // S^T tiles: bias^T as accumulator init, loaded at use
    floatx16 s0, s1;
#pragma unroll
    for (int rr = 0; rr < 4; ++rr) {
      float4 b0 = bp[rr * 64];
      float4 b1 = bp[(4 + rr) * 64];
      s0[rr * 4 + 0] = b0.x; s0[rr * 4 + 1] = b0.y; s0[rr * 4 + 2] = b0.z; s0[rr * 4 + 3] = b0.w;
      s1[rr * 4 + 0] = b1.x; s1[rr * 4 + 1] = b1.y; s1[rr * 4 + 2] = b1.z; s1[rr * 4 + 3] = b1.w;
    }
    bp += 512;

    if (c < 15) {                  // register prefetch of chunk c+1 K/V
      kp += (size_t)64 * H_ * DH_;
      vp += 64;
#pragma unroll
      for (int it = 0; it < 2; ++it) {
        rk[it] = *(const short8*)(kp + (size_t)it * 32 * H_ * DH_);
        rv[it] = *(const short8*)(vp + (size_t)it * 32 * L_);
      }
    }

#pragma unroll
    for (int ks = 0; ks < 4; ++ks) {
      half8 bk0 = *(const half8*)&lK[c32][ks * 16 + hi * 8];
      half8 bk1 = *(const half8*)&lK[32 + c32][ks * 16 + hi * 8];
      s0 = __builtin_amdgcn_mfma_f32_32x32x16_f16(bk0, aq[ks], s0, 0, 0, 0);
      s1 = __builtin_amdgcn_mfma_f32_32x32x16_f16(bk1, aq[ks], s1, 0, 0, 0);
    }

    // softmax weights (exp2; shift folded into bias) -> in-register bf16 PV A-frags
    union { short8 v[4]; unsigned u[16]; } ap;
#pragma unroll
    for (int reg = 0; reg < 16; ++reg) {
      float p0 = EXP2(s0[reg]);
      float p1 = EXP2(s1[reg]);
      ap.u[reg] = pack_bf2(p0, p1);
      if (reg & 1) rsum1 += p0 + p1; else rsum0 += p0 + p1;
    }

    // O += P V (2 dh-tiles), bf16
#pragma unroll
    for (int ks = 0; ks < 4; ++ks) {
      short8 bv0 = *(const short8*)&lVt[c32][ks * 16 + hi * 8];
      short8 bv1 = *(const short8*)&lVt[32 + c32][ks * 16 + hi * 8];
      acc0 = __builtin_amdgcn_mfma_f32_32x32x16_bf16(ap.v[ks], bv0, acc0, 0, 0, 0);
      acc1 = __builtin_amdgcn_mfma_f32_32x32x16_bf16(ap.v[ks], bv1, acc1, 0, 0, 0);
    }
  }

  // rowsum: combine hi halves, broadcast via wave-private LDS.
  float rsum = rsum0 + rsum1;
  rsum += __shfl_xor(rsum, 32, 64);
  if (hi == 0) lRS[w][c32] = rsum;

  // epilogue: normalize (acc C-layout: row=(reg&3)+8*(reg>>2)+4*hi, col=dh=c32)
#pragma unroll
  for (int reg = 0; reg < 16; ++reg) {
    int rl = (reg & 3) + 8 * (reg >> 2) + 4 * hi;
    float inv = 1.0f / lRS[w][rl];
    int row = qr0 + rl;
    size_t obase = ((size_t)((b * L_ + row) * H_ + h)) * DH_;
    o[obase + c32]      = f2h(acc0[reg] * inv);
    o[obase + 32 + c32] = f2h(acc1[reg] * inv);
  }
}

// ---------------------------------------------------------------- launch
extern "C" void kernel_launch(void* const* d_in, const int* in_sizes, int n_in,
                              void* d_out, int out_size, void* d_ws, size_t ws_size,
                              hipStream_t stream) {
  const float* x    = (const float*)d_in[0];
  const float* mask = (const float*)d_in[1];
  const float* Wk   = (const float*)d_in[2];
  const float* Wv   = (const float*)d_in[3];
  const float* Wq   = (const float*)d_in[4];
  const float* Wo   = (const float*)d_in[5];

  char* ws = (char*)d_ws;
  u16* xf    = (u16*)(ws);                        // 16 MB x f16 ; later attn out f16
  u16* aout  = xf;
  u16* kf    = (u16*)(ws + (16ull << 20));        // 16 MB k f16
  u16* vtb   = (u16*)(ws + (32ull << 20));        // 16 MB transposed+permuted V bf16
  float* biasP = (float*)(ws + (48ull << 20));    // 4 MB permuted bias^T (log2e-scaled)
  u16* wqf   = (u16*)(ws + (52ull << 20));        // 2 MB each, f16 weights
  u16* wkf   = (u16*)(ws + (54ull << 20));
  u16* wvf   = (u16*)(ws + (56ull << 20));
  u16* wof   = (u16*)(ws + (58ull << 20));
  // d_out (32 MB): qf (lower 16) -> final fp32 out overwrites
  u16* qf = (u16*)d_out;

  cast_all<<<16384, 256, 0, stream>>>(x, Wq, Wk, Wv, Wo, mask,
                                      xf, wqf, wkf, wvf, wof, biasP);

  gemm_qkv<<<dim3(24, 64), 256, 0, stream>>>(xf, wqf, wkf, wvf, qf, kf, vtb);

  attn_kernel<<<dim3(B_ * H_, L_ / 128), 256, 0, stream>>>(qf, kf, vtb, biasP, aout);

  gemm_fin<<<dim3(D_ / 128, (B_ * L_) / 128), 256, 0, stream>>>(
      aout, wof, (float*)d_out, B_ * L_, D_, D_);
}